// Round 22
// baseline (328.143 us; speedup 1.0000x reference)
//
#include <hip/hip_runtime.h>
#include <hip/hip_bf16.h>

// LRRNN: B=64, dz=16, K=16, N=1024, dx=128, T=500 (T read from input 8).
// 64 blocks, 8 waves x 128 N-rows, 2 waves/SIMD. R17/R20 skeleton (champion,
// ~321us): phase A (8 indep X-MFMAs -> relu/pack -> 4x x32 n@R) -> lgkm-bar
// -> wave0 window (reduce + z update + packed zbuf broadcast) overlapped
// with waves 1-7 lagged readout (swapped z^T*Bobs MFMA -> ONE dwordx4 store
// per tile) -> lgkm-bar -> 8B zbuf read. lgkm-only barriers.
// R22: PIN MFMA RESULTS TO ARCH VGPRs via zero-instruction empty asm with
// "+v" constraints. VGPR_Count=68 proves persistents are AGPR-banked; if
// regalloc also puts MFMA D-results in AGPRs, every relu/add consumer pays
// v_accvgpr_read -- the ~90 phantom VALU inst/wave/step in the ledger
// (measured ~195 vs ~105 static). The "v" pin forces D into v-class with no
// emitted instruction and no MFMA hazard risk (builtins keep their NOPs).

typedef __attribute__((ext_vector_type(4))) short short4v;
typedef __attribute__((ext_vector_type(8))) short short8v;
typedef __attribute__((ext_vector_type(4))) float float4v;

#define BB 64
#define DZ 16
#define KC 16
#define NN 1024
#define DX 128
#define NW 8                    // waves per block
#define ITER (NN / (16 * NW))   // 8 row-tiles per wave
#define NH (ITER / 2)           // 4 x32 n-MFMAs per wave

// execution barrier + LDS publish; NO vmcnt drain
#define BARRIER_LGKM() asm volatile("s_waitcnt lgkmcnt(0)\n\ts_barrier" ::: "memory")
// zero-instruction pin: force value into arch-VGPR class (not AGPR)
#define PIN_V(x) asm volatile("" : "+v"(x))

union FragAB {
  short4v s;
  unsigned u[2];
};
union Frag8 {
  short8v s8;
  short4v s4[2];
};

// f32x2 -> packed bf16x2 in ONE VALU op (RNE), inputs/outputs pinned "v".
__device__ inline unsigned cvt_pk_bf16(float lo, float hi) {
  unsigned r;
  asm("v_cvt_pk_bf16_f32 %0, %1, %2" : "=v"(r) : "v"(lo), "v"(hi));
  return r;
}

__device__ inline short4v pack_bf16x4(float a, float b, float c, float d) {
  FragAB x;
  x.u[0] = cvt_pk_bf16(a, b);
  x.u[1] = cvt_pk_bf16(c, d);
  return x.s;
}

// every branch __has_builtin-guarded: the HOST pass must never see a branch
// whose builtin it can't resolve (falls through to never-executed asm).
__device__ inline float4v mfma_bf16(short4v a, short4v b, float4v c) {
#if __has_builtin(__builtin_amdgcn_mfma_f32_16x16x16bf16_1k)
  return __builtin_amdgcn_mfma_f32_16x16x16bf16_1k(a, b, c, 0, 0, 0);
#else
  float4v d;
  asm("v_mfma_f32_16x16x16_bf16 %0, %1, %2, %3"
      : "=v"(d) : "v"(a), "v"(b), "v"(c));
  return d;
#endif
}

__device__ inline float4v mfma_bf16_x32(short8v a, short8v b, float4v c) {
#if __has_builtin(__builtin_amdgcn_mfma_f32_16x16x32_bf16)
  return __builtin_amdgcn_mfma_f32_16x16x32_bf16(a, b, c, 0, 0, 0);
#else
  float4v d;
  asm("v_mfma_f32_16x16x32_bf16 %0, %1, %2, %3"
      : "=v"(d) : "v"(a), "v"(b), "v"(c));
  return d;
#endif
}

__global__ __launch_bounds__(64 * NW, 1)
void lrrnn_fused(const float* __restrict__ z0, const float* __restrict__ Adec,
                 const float* __restrict__ nmat, const float* __restrict__ mmat,
                 const float* __restrict__ hvec, const float* __restrict__ hzvec,
                 const float* __restrict__ Bobs, const float* __restrict__ Bias,
                 const int* __restrict__ Tptr, float* __restrict__ out)
{
  const int T    = Tptr[0];
  const int b    = blockIdx.x;
  const int tid  = threadIdx.x;
  const int wave = tid >> 6;
  const int lane = tid & 63;
  const int g    = lane >> 4;   // 0..3  (quad group)
  const int c    = lane & 15;   // 0..15 (column / row-in-tile)

  // single-buffered partials: wave0's reads complete before its lgkm+bar2;
  // peers' next writes are post-bar2 (R6/R10-proven).
  __shared__ float4v part[NW][64];
  __shared__ short4v zbuf[64];       // packed bf16 z broadcast (8 B/lane)

  // ---- one-time fragment preload (weights shared across blocks; L2-resident) ----
  // m A-frag (x16): A[row=c][k=4g+j] = m[(rowbase+c)*16 + 4g+j]
  // n A-frag (x32): slot j<4 -> n[c*1024 + rb+4g+j], j>=4 -> n[c*1024 + rb+16+4g+j-4]
  // negH C-frag: C[row=4g+r][col] = -h[rowbase + 4g+r]
  FragAB mf[ITER];
  Frag8  nf8[NH];
  float4v negH[ITER];
#pragma unroll
  for (int i = 0; i < ITER; ++i) {
    const int rowbase = wave * (16 * ITER) + i * 16;
    float4v mv = *(const float4v*)(mmat + (rowbase + c) * DZ + g * 4);
    mf[i].s = pack_bf16x4(mv[0], mv[1], mv[2], mv[3]);
    float4v hv = *(const float4v*)(hvec + rowbase + g * 4);
    negH[i][0] = -hv[0]; negH[i][1] = -hv[1];
    negH[i][2] = -hv[2]; negH[i][3] = -hv[3];
  }
#pragma unroll
  for (int i = 0; i < NH; ++i) {
    const int rb0 = wave * (16 * ITER) + (2 * i) * 16;
    float4v nv0 = *(const float4v*)(nmat + c * NN + rb0 + g * 4);
    float4v nv1 = *(const float4v*)(nmat + c * NN + rb0 + 16 + g * 4);
    nf8[i].s4[0] = pack_bf16x4(nv0[0], nv0[1], nv0[2], nv0[3]);
    nf8[i].s4[1] = pack_bf16x4(nv1[0], nv1[1], nv1[2], nv1[3]);
  }

  // decay / bias-z frags (C-layout rows = z = 4g+r); wave0 is the z owner
  const float4v Af  = *(const float4v*)(Adec + g * 4);
  const float4v hzf = *(const float4v*)(hzvec + g * 4);
  const float4v zerov = {0.f, 0.f, 0.f, 0.f};
  // loop-invariant accumulator-0 init (hz folded into wave0's partial)
  const float4v c0init = (wave == 0) ? hzf : zerov;

  // ---- readout tiles: tile tau handled by wave (tau%7)+1; wave1 also has
  // tile 7. wave0 does none (it owns the reduce window).
  // SWAPPED readout (R17): A = zb, B[kk=4g+j][x=c] = Bobs[(4g+j)*128+xb+c],
  // C = Bias[xb+c] replicated; D[k=4g+rr][x=c] -> one dwordx4 per tile.
  const int t0 = (wave >= 1) ? (wave - 1) : 0;
  const int nt = (wave == 1) ? 2 : ((wave == 0) ? 0 : 1);
  int tiles[2] = {t0, 7};
  FragAB bobsF[2];
  float4v biasF[2];
  unsigned oof[2];               // element offset of (x=xb+c, t=0, k=4g)
#pragma unroll
  for (int s = 0; s < 2; ++s) {
    const int xb = tiles[s] * 16;
    bobsF[s].s = pack_bf16x4(Bobs[(4 * g + 0) * DX + xb + c],
                             Bobs[(4 * g + 1) * DX + xb + c],
                             Bobs[(4 * g + 2) * DX + xb + c],
                             Bobs[(4 * g + 3) * DX + xb + c]);
    const float bx = Bias[xb + c];
    biasF[s][0] = bx; biasF[s][1] = bx; biasF[s][2] = bx; biasF[s][3] = bx;
    oof[s] = (unsigned)(b * DX + xb + c) * (unsigned)T * KC + (unsigned)(g * 4);
  }

  // z state: f32 master in wave0 only; all waves track packed bf16 zb
  float4v zf;
#pragma unroll
  for (int j = 0; j < 4; ++j)
    zf[j] = z0[b * DZ * KC + (g * 4 + j) * KC + c];
  FragAB zb;
  zb.s = pack_bf16x4(zf[0], zf[1], zf[2], zf[3]);

  for (int t = 0; t < T; ++t) {
    // ---- phase A: 8 indep X-MFMAs (D pinned to VGPR) -> relu/pack -> n@R ----
    float4v xv[ITER];
#pragma unroll
    for (int i = 0; i < ITER; ++i) {
      xv[i] = mfma_bf16(mf[i].s, zb.s, negH[i]);
      PIN_V(xv[i]);                    // force D into arch VGPR (no accvgpr_read)
    }

    Frag8 R8[NH];
#pragma unroll
    for (int i = 0; i < NH; ++i) {
      const float4v x0 = xv[2 * i], x1 = xv[2 * i + 1];
      R8[i].s4[0] = pack_bf16x4(fmaxf(x0[0], 0.f), fmaxf(x0[1], 0.f),
                                fmaxf(x0[2], 0.f), fmaxf(x0[3], 0.f));
      R8[i].s4[1] = pack_bf16x4(fmaxf(x1[0], 0.f), fmaxf(x1[1], 0.f),
                                fmaxf(x1[2], 0.f), fmaxf(x1[3], 0.f));
    }

    float4v a0 = mfma_bf16_x32(nf8[0].s8, R8[0].s8, c0init);
    float4v a1 = mfma_bf16_x32(nf8[1].s8, R8[1].s8, zerov);
    a0 = mfma_bf16_x32(nf8[2].s8, R8[2].s8, a0);
    a1 = mfma_bf16_x32(nf8[3].s8, R8[3].s8, a1);
    PIN_V(a0);
    PIN_V(a1);                         // zp consumers read VGPRs directly
    const float4v zp = a0 + a1;

    if (wave != 0) part[wave][lane] = zp;
    BARRIER_LGKM();    // barrier 1: partials published (no vmcnt drain)

    if (wave == 0) {
      // ---- reduce + z update + broadcast (the serial window) ----
      const float4v p1 = part[1][lane];
      const float4v p2 = part[2][lane];
      const float4v p3 = part[3][lane];
      const float4v p4 = part[4][lane];
      const float4v p5 = part[5][lane];
      const float4v p6 = part[6][lane];
      const float4v p7 = part[7][lane];
      const float4v tot = ((zp + p1) + (p2 + p3)) + ((p4 + p5) + (p6 + p7));
#pragma unroll
      for (int j = 0; j < 4; ++j)
        zf[j] = fmaf(Af[j], zf[j], tot[j]);
      zb.s = pack_bf16x4(zf[0], zf[1], zf[2], zf[3]);
      zbuf[lane] = zb.s;
    } else if (t > 0) {
      // ---- lagged readout fills the window: zb = z_t -> out index t-1 ----
      const unsigned tk = (unsigned)(t - 1) * KC;
#pragma unroll
      for (int s = 0; s < 2; ++s) {
        if (s < nt) {
          float4v o = mfma_bf16(zb.s, bobsF[s].s, biasF[s]);  // SWAPPED
          *(float4v*)(out + oof[s] + tk) = o;                 // 16B store
        }
      }
    }
    BARRIER_LGKM();    // barrier 2: zbuf published (no vmcnt drain)

    if (wave != 0) zb.s = zbuf[lane];   // 8 B broadcast (2-way alias: free)
  }

  // ---- epilogue: final readout, index T-1 from zb = z_T ----
  if (wave != 0) {
    const unsigned tk = (unsigned)(T - 1) * KC;
#pragma unroll
    for (int s = 0; s < 2; ++s) {
      if (s < nt) {
        float4v o = mfma_bf16(zb.s, bobsF[s].s, biasF[s]);    // SWAPPED
        *(float4v*)(out + oof[s] + tk) = o;                   // 16B store
      }
    }
  }
}

extern "C" void kernel_launch(void* const* d_in, const int* in_sizes, int n_in,
                              void* d_out, int out_size, void* d_ws, size_t ws_size,
                              hipStream_t stream) {
  const float* z0   = (const float*)d_in[0];
  const float* A    = (const float*)d_in[1];
  const float* nmat = (const float*)d_in[2];
  const float* mmat = (const float*)d_in[3];
  const float* h    = (const float*)d_in[4];
  const float* hz   = (const float*)d_in[5];
  const float* Bobs = (const float*)d_in[6];
  const float* Bias = (const float*)d_in[7];
  const int*   T    = (const int*)d_in[8];
  (void)in_sizes; (void)n_in; (void)out_size; (void)d_ws; (void)ws_size;
  lrrnn_fused<<<dim3(BB), dim3(64 * NW), 0, stream>>>(
      z0, A, nmat, mmat, h, hz, Bobs, Bias, T, (float*)d_out);
}

// Round 23
// 323.050 us; speedup vs baseline: 1.0158x; 1.0158x over previous
//
#include <hip/hip_runtime.h>
#include <hip/hip_bf16.h>

// LRRNN: B=64, dz=16, K=16, N=1024, dx=128, T=500 (T read from input 8).
// CHAMPION (R20, 321.3us; reverted after R21/R22 nulls).
// 64 blocks (structural: 16 MFMA columns = one batch's 16 sequences; N=1024
// reduction is intra-block), 8 waves x 128 N-rows, 2 waves/SIMD (measured
// optimum of the 1/2/4 scan). Per step:
//   phase A: 8 indep X-MFMAs (16x16x16, C=-h folded) -> relu/pack -> 4x
//     mfma 16x16x32 n@R (k-permutation-invariant packing, 2 chains)
//   -> lgkm-only barrier (NO vmcnt drain: readout stores never drained)
//   -> wave0 window: 7-partial reduce + z'=A*z+tot (f32 master) + packed
//      bf16 zbuf broadcast || waves 1-7: lagged readout out[t-1] via
//      SWAPPED z^T*Bobs MFMA (zb is A by layout symmetry) -> ONE
//      global_store_dwordx4 per tile
//   -> lgkm-only barrier -> 8B zbuf read.
// Floor analysis (23-round search): 500 serial steps x (13-MFMA dep chain +
// 2 rendezvous + 2 LDS round trips) ~= 1540 cyc/step; no pipe >13% global.
// Falsified: barrier count, reduce redundancy/atomics/flags, store BW
// (split-kernel R18), vmcnt drains, setprio, wave count, AGPR placement.

typedef __attribute__((ext_vector_type(4))) short short4v;
typedef __attribute__((ext_vector_type(8))) short short8v;
typedef __attribute__((ext_vector_type(4))) float float4v;

#define BB 64
#define DZ 16
#define KC 16
#define NN 1024
#define DX 128
#define NW 8                    // waves per block
#define ITER (NN / (16 * NW))   // 8 row-tiles per wave
#define NH (ITER / 2)           // 4 x32 n-MFMAs per wave

// execution barrier + LDS publish; NO vmcnt drain
#define BARRIER_LGKM() asm volatile("s_waitcnt lgkmcnt(0)\n\ts_barrier" ::: "memory")

union FragAB {
  short4v s;
  __hip_bfloat162 h2[2];
};
union Frag8 {
  short8v s8;
  short4v s4[2];
};

__device__ inline short4v pack_bf16x4(float a, float b, float c, float d) {
  FragAB u;
  u.h2[0] = __float22bfloat162_rn(make_float2(a, b));
  u.h2[1] = __float22bfloat162_rn(make_float2(c, d));
  return u.s;
}

// every branch __has_builtin-guarded: the HOST pass must never see a branch
// whose builtin it can't resolve (falls through to never-executed asm).
__device__ inline float4v mfma_bf16(short4v a, short4v b, float4v c) {
#if __has_builtin(__builtin_amdgcn_mfma_f32_16x16x16bf16_1k)
  return __builtin_amdgcn_mfma_f32_16x16x16bf16_1k(a, b, c, 0, 0, 0);
#else
  float4v d;
  asm("v_mfma_f32_16x16x16_bf16 %0, %1, %2, %3"
      : "=v"(d) : "v"(a), "v"(b), "v"(c));
  return d;
#endif
}

__device__ inline float4v mfma_bf16_x32(short8v a, short8v b, float4v c) {
#if __has_builtin(__builtin_amdgcn_mfma_f32_16x16x32_bf16)
  return __builtin_amdgcn_mfma_f32_16x16x32_bf16(a, b, c, 0, 0, 0);
#else
  float4v d;
  asm("v_mfma_f32_16x16x32_bf16 %0, %1, %2, %3"
      : "=v"(d) : "v"(a), "v"(b), "v"(c));
  return d;
#endif
}

__global__ __launch_bounds__(64 * NW, 1)
void lrrnn_fused(const float* __restrict__ z0, const float* __restrict__ Adec,
                 const float* __restrict__ nmat, const float* __restrict__ mmat,
                 const float* __restrict__ hvec, const float* __restrict__ hzvec,
                 const float* __restrict__ Bobs, const float* __restrict__ Bias,
                 const int* __restrict__ Tptr, float* __restrict__ out)
{
  const int T    = Tptr[0];
  const int b    = blockIdx.x;
  const int tid  = threadIdx.x;
  const int wave = tid >> 6;
  const int lane = tid & 63;
  const int g    = lane >> 4;   // 0..3  (quad group)
  const int c    = lane & 15;   // 0..15 (column / row-in-tile)

  // single-buffered partials: wave0's reads complete before its lgkm+bar2;
  // peers' next writes are post-bar2 (R6/R10-proven).
  __shared__ float4v part[NW][64];
  __shared__ short4v zbuf[64];       // packed bf16 z broadcast (8 B/lane)

  // ---- one-time fragment preload (weights shared across blocks; L2-resident) ----
  // m A-frag (x16): A[row=c][k=4g+j] = m[(rowbase+c)*16 + 4g+j]
  // n A-frag (x32): slot j<4 -> n[c*1024 + rb+4g+j], j>=4 -> n[c*1024 + rb+16+4g+j-4]
  // negH C-frag: C[row=4g+r][col] = -h[rowbase + 4g+r]
  FragAB mf[ITER];
  Frag8  nf8[NH];
  float4v negH[ITER];
#pragma unroll
  for (int i = 0; i < ITER; ++i) {
    const int rowbase = wave * (16 * ITER) + i * 16;
    float4v mv = *(const float4v*)(mmat + (rowbase + c) * DZ + g * 4);
    mf[i].s = pack_bf16x4(mv[0], mv[1], mv[2], mv[3]);
    float4v hv = *(const float4v*)(hvec + rowbase + g * 4);
    negH[i][0] = -hv[0]; negH[i][1] = -hv[1];
    negH[i][2] = -hv[2]; negH[i][3] = -hv[3];
  }
#pragma unroll
  for (int i = 0; i < NH; ++i) {
    const int rb0 = wave * (16 * ITER) + (2 * i) * 16;
    float4v nv0 = *(const float4v*)(nmat + c * NN + rb0 + g * 4);
    float4v nv1 = *(const float4v*)(nmat + c * NN + rb0 + 16 + g * 4);
    nf8[i].s4[0] = pack_bf16x4(nv0[0], nv0[1], nv0[2], nv0[3]);
    nf8[i].s4[1] = pack_bf16x4(nv1[0], nv1[1], nv1[2], nv1[3]);
  }

  // decay / bias-z frags (C-layout rows = z = 4g+r); wave0 is the z owner
  const float4v Af  = *(const float4v*)(Adec + g * 4);
  const float4v hzf = *(const float4v*)(hzvec + g * 4);
  const float4v zerov = {0.f, 0.f, 0.f, 0.f};

  // ---- readout tiles: tile tau handled by wave (tau%7)+1; wave1 also has
  // tile 7. wave0 does none (it owns the reduce window).
  // SWAPPED readout (R17): A = zb, B[kk=4g+j][x=c] = Bobs[(4g+j)*128+xb+c],
  // C = Bias[xb+c] replicated; D[k=4g+rr][x=c] -> one dwordx4 per tile.
  const int t0 = (wave >= 1) ? (wave - 1) : 0;
  const int nt = (wave == 1) ? 2 : ((wave == 0) ? 0 : 1);
  int tiles[2] = {t0, 7};
  FragAB bobsF[2];
  float4v biasF[2];
  unsigned oof[2];               // element offset of (x=xb+c, t=0, k=4g)
#pragma unroll
  for (int s = 0; s < 2; ++s) {
    const int xb = tiles[s] * 16;
    bobsF[s].s = pack_bf16x4(Bobs[(4 * g + 0) * DX + xb + c],
                             Bobs[(4 * g + 1) * DX + xb + c],
                             Bobs[(4 * g + 2) * DX + xb + c],
                             Bobs[(4 * g + 3) * DX + xb + c]);
    const float bx = Bias[xb + c];
    biasF[s][0] = bx; biasF[s][1] = bx; biasF[s][2] = bx; biasF[s][3] = bx;
    oof[s] = (unsigned)(b * DX + xb + c) * (unsigned)T * KC + (unsigned)(g * 4);
  }

  // z state: f32 master in wave0 only; all waves track packed bf16 zb
  float4v zf;
#pragma unroll
  for (int j = 0; j < 4; ++j)
    zf[j] = z0[b * DZ * KC + (g * 4 + j) * KC + c];
  FragAB zb;
  zb.s = pack_bf16x4(zf[0], zf[1], zf[2], zf[3]);

  for (int t = 0; t < T; ++t) {
    // ---- phase A: 8 indep X-MFMAs -> relu/pack -> 4x x32 n@R ----
    float4v xv[ITER];
#pragma unroll
    for (int i = 0; i < ITER; ++i)
      xv[i] = mfma_bf16(mf[i].s, zb.s, negH[i]);

    Frag8 R8[NH];
#pragma unroll
    for (int i = 0; i < NH; ++i) {
      const float4v x0 = xv[2 * i], x1 = xv[2 * i + 1];
      R8[i].s4[0] = pack_bf16x4(fmaxf(x0[0], 0.f), fmaxf(x0[1], 0.f),
                                fmaxf(x0[2], 0.f), fmaxf(x0[3], 0.f));
      R8[i].s4[1] = pack_bf16x4(fmaxf(x1[0], 0.f), fmaxf(x1[1], 0.f),
                                fmaxf(x1[2], 0.f), fmaxf(x1[3], 0.f));
    }

    float4v a0 = mfma_bf16_x32(nf8[0].s8, R8[0].s8, (wave == 0) ? hzf : zerov);
    float4v a1 = mfma_bf16_x32(nf8[1].s8, R8[1].s8, zerov);
    a0 = mfma_bf16_x32(nf8[2].s8, R8[2].s8, a0);
    a1 = mfma_bf16_x32(nf8[3].s8, R8[3].s8, a1);
    const float4v zp = a0 + a1;

    if (wave != 0) part[wave][lane] = zp;
    BARRIER_LGKM();    // barrier 1: partials published (no vmcnt drain)

    if (wave == 0) {
      // ---- reduce + z update + broadcast (the serial window) ----
      const float4v p1 = part[1][lane];
      const float4v p2 = part[2][lane];
      const float4v p3 = part[3][lane];
      const float4v p4 = part[4][lane];
      const float4v p5 = part[5][lane];
      const float4v p6 = part[6][lane];
      const float4v p7 = part[7][lane];
      const float4v tot = ((zp + p1) + (p2 + p3)) + ((p4 + p5) + (p6 + p7));
#pragma unroll
      for (int j = 0; j < 4; ++j)
        zf[j] = fmaf(Af[j], zf[j], tot[j]);
      zb.s = pack_bf16x4(zf[0], zf[1], zf[2], zf[3]);
      zbuf[lane] = zb.s;
    } else if (t > 0) {
      // ---- lagged readout fills the window: zb = z_t -> out index t-1 ----
      const unsigned tk = (unsigned)(t - 1) * KC;
#pragma unroll
      for (int s = 0; s < 2; ++s) {
        if (s < nt) {
          float4v o = mfma_bf16(zb.s, bobsF[s].s, biasF[s]);  // SWAPPED
          *(float4v*)(out + oof[s] + tk) = o;                 // 16B store
        }
      }
    }
    BARRIER_LGKM();    // barrier 2: zbuf published (no vmcnt drain)

    if (wave != 0) zb.s = zbuf[lane];   // 8 B broadcast (2-way alias: free)
  }

  // ---- epilogue: final readout, index T-1 from zb = z_T ----
  if (wave != 0) {
    const unsigned tk = (unsigned)(T - 1) * KC;
#pragma unroll
    for (int s = 0; s < 2; ++s) {
      if (s < nt) {
        float4v o = mfma_bf16(zb.s, bobsF[s].s, biasF[s]);    // SWAPPED
        *(float4v*)(out + oof[s] + tk) = o;                   // 16B store
      }
    }
  }
}

extern "C" void kernel_launch(void* const* d_in, const int* in_sizes, int n_in,
                              void* d_out, int out_size, void* d_ws, size_t ws_size,
                              hipStream_t stream) {
  const float* z0   = (const float*)d_in[0];
  const float* A    = (const float*)d_in[1];
  const float* nmat = (const float*)d_in[2];
  const float* mmat = (const float*)d_in[3];
  const float* h    = (const float*)d_in[4];
  const float* hz   = (const float*)d_in[5];
  const float* Bobs = (const float*)d_in[6];
  const float* Bias = (const float*)d_in[7];
  const int*   T    = (const int*)d_in[8];
  (void)in_sizes; (void)n_in; (void)out_size; (void)d_ws; (void)ws_size;
  lrrnn_fused<<<dim3(BB), dim3(64 * NW), 0, stream>>>(
      z0, A, nmat, mmat, h, hz, Bobs, Bias, T, (float*)d_out);
}